// Round 1
// baseline (499.742 us; speedup 1.0000x reference)
//
#include <hip/hip_runtime.h>
#include <stdint.h>

// VectorQuantizer: z[32768,512] f32, weight[8192,512] f32 ->
//   out[0 .. 32768*512) = z_q = weight[argmin_k ||z-e_k||^2]  (exact fp32 rows)
//   out[32768*512]      = perplexity
//
// Pipeline:
//  1) k_prep_z / k_prep_w: fp32 -> bf16 copies (+ exact fp32 row norms c_k)
//  2) k_phase1: bf16-MFMA  d~ = c_k - 2 z.e_k ; per token keep top-2 packed keys
//     (quantized distance | 13-bit code idx) per 128 code-cells -> slotbuf
//  3) k_select: global min; candidates within MARGIN re-ranked with exact f64
//     dots (hot cells fully rescanned); writes idx + histogram atomics
//  4) k_gather: z_q rows ; k_perp: perplexity
//
// ws layout (bytes):
//   zb    @ 0         : 32 MB  (bf16 z)
//   wb    @ 33554432  :  8 MB  (bf16 w)
//   cnorm @ 41943040  : 32 KB  (f32 ||e_k||^2)
//   slot  @ 41975808  : 32 MB  ([token][128 cells][2] f32 packed keys)
//   idx   @ 75530240  : 128 KB (i32)
//   counts@ 75661312  : 32 KB  (u32)

#define NTOK 32768
#define NE   8192
#define DIM  512
#define MARGIN 4.0f

typedef __attribute__((ext_vector_type(8))) short bf16x8;
typedef __attribute__((ext_vector_type(4))) float f32x4;

__device__ __forceinline__ unsigned int f2bf1(float x) {
  unsigned int u = __float_as_uint(x);
  return (u + 0x7FFFu + ((u >> 16) & 1u)) >> 16;
}
__device__ __forceinline__ unsigned int packbf2(float lo, float hi) {
  return f2bf1(lo) | (f2bf1(hi) << 16);
}

__device__ __forceinline__ void gl_lds16(const void* g, void* l) {
  __builtin_amdgcn_global_load_lds(
      (const __attribute__((address_space(1))) void*)g,
      (__attribute__((address_space(3))) void*)l, 16, 0, 0);
}

__global__ void k_prep_z(const float* __restrict__ z, unsigned int* __restrict__ zb) {
  int i = blockIdx.x * 256 + threadIdx.x;  // one thread per 8 floats; grid exact
  const float4* zp = (const float4*)z + (size_t)i * 2;
  float4 a = zp[0], b = zp[1];
  uint4 o;
  o.x = packbf2(a.x, a.y); o.y = packbf2(a.z, a.w);
  o.z = packbf2(b.x, b.y); o.w = packbf2(b.z, b.w);
  ((uint4*)zb)[i] = o;
}

__global__ void k_prep_w(const float* __restrict__ w, unsigned int* __restrict__ wb,
                         float* __restrict__ cnorm) {
  int row  = blockIdx.x * 4 + (threadIdx.x >> 6);  // one wave per code row
  int lane = threadIdx.x & 63;
  const float4* wp = (const float4*)(w + (size_t)row * DIM) + lane * 2;
  float4 a = wp[0], b = wp[1];
  uint4 o;
  o.x = packbf2(a.x, a.y); o.y = packbf2(a.z, a.w);
  o.z = packbf2(b.x, b.y); o.w = packbf2(b.z, b.w);
  ((uint4*)wb)[(size_t)row * 64 + lane] = o;
  float s = a.x * a.x + a.y * a.y + a.z * a.z + a.w * a.w
          + b.x * b.x + b.y * b.y + b.z * b.z + b.w * b.w;
#pragma unroll
  for (int m = 1; m < 64; m <<= 1) s += __shfl_xor(s, m);
  if (lane == 0) cnorm[row] = s;
}

// block: 256 thr = 4 waves (wr,wc in 2x2), tile 64 tokens x 128 codes, BK=64.
// grid: 1024 = 512 token-blocks x 2 code-splits (4096 codes each, 32 ct tiles).
__global__ void __launch_bounds__(256) k_phase1(
    const unsigned short* __restrict__ zb, const unsigned short* __restrict__ wb,
    const float* __restrict__ cnorm, float* __restrict__ slotbuf) {
  __shared__ unsigned short Abuf[64 * 64];   //  8 KB  [tok][k] bf16, xor-swizzled
  __shared__ unsigned short Bbuf[128 * 64];  // 16 KB  [code][k]

  const int tid  = threadIdx.x;
  const int lane = tid & 63;
  const int wv   = tid >> 6;
  const int wr   = wv >> 1;
  const int wc   = wv & 1;
  const int tb    = blockIdx.x >> 1;
  const int split = blockIdx.x & 1;

  const int l8   = lane >> 3;
  const int l15  = lane & 15;
  // staging source col-byte, pre-swizzled so linear global_load_lds dest holds
  // element (row, col ^ ((row&7)<<4)); row&7 == lane>>3 for every issue.
  const int cbsw = ((lane & 7) ^ l8) << 4;

  const char* zsrc = (const char*)zb + (size_t)(tb * 64 + wv * 16 + l8) * 1024 + cbsw;
  const char* wsrc = (const char*)wb + (size_t)(split * 4096 + wv * 32 + l8) * 1024 + cbsw;

  char* Ab = (char*)Abuf;
  char* Bb = (char*)Bbuf;
  char* dstA = Ab + wv * 2048;  // wave-uniform LDS bases (+lane*16 by HW)
  char* dstB = Bb + wv * 4096;

  // frag read col-bytes: (ks*64 + (lane>>4)*16) ^ ((lane&7)<<4)  (row&7==lane&7)
  const int csw0 = (((lane >> 4) << 4)) ^ ((lane & 7) << 4);
  const int csw1 = (64 + ((lane >> 4) << 4)) ^ ((lane & 7) << 4);
  const int arow0 = (wr * 32 + l15) << 7;
  const int arow1 = (wr * 32 + 16 + l15) << 7;
  const int brow0 = (wc * 64 + 0 + l15) << 7;
  const int brow1 = (wc * 64 + 16 + l15) << 7;
  const int brow2 = (wc * 64 + 32 + l15) << 7;
  const int brow3 = (wc * 64 + 48 + l15) << 7;

  const float BIG = 3.0e38f;
  float m1s[2][4][2], m2s[2][4][2];
#pragma unroll
  for (int fi = 0; fi < 2; ++fi)
#pragma unroll
    for (int r = 0; r < 4; ++r)
#pragma unroll
      for (int c2 = 0; c2 < 2; ++c2) { m1s[fi][r][c2] = BIG; m2s[fi][r][c2] = BIG; }

  const unsigned int KMASK = 0xFFFFE000u;

  for (int ct = 0; ct < 32; ++ct) {
    const int codebase = split * 4096 + ct * 128 + wc * 64 + l15;
    float cf0 = cnorm[codebase + 0];
    float cf1 = cnorm[codebase + 16];
    float cf2 = cnorm[codebase + 32];
    float cf3 = cnorm[codebase + 48];

    f32x4 acc[2][4];
    f32x4 zz = {0.f, 0.f, 0.f, 0.f};
#pragma unroll
    for (int fi = 0; fi < 2; ++fi)
#pragma unroll
      for (int fj = 0; fj < 4; ++fj) acc[fi][fj] = zz;

    const char* wct = wsrc + (size_t)ct * 128 * 1024;

    for (int kc = 0; kc < 8; ++kc) {
      __syncthreads();
      const char* ak = zsrc + kc * 128;
      gl_lds16(ak, dstA);
      gl_lds16(ak + 8192, dstA + 1024);
      const char* bk = wct + kc * 128;
      gl_lds16(bk, dstB);
      gl_lds16(bk + 8192, dstB + 1024);
      gl_lds16(bk + 16384, dstB + 2048);
      gl_lds16(bk + 24576, dstB + 3072);
      __syncthreads();
#pragma unroll
      for (int ks = 0; ks < 2; ++ks) {
        const int cs = ks ? csw1 : csw0;
        bf16x8 a0 = *(const bf16x8*)(Ab + arow0 + cs);
        bf16x8 a1 = *(const bf16x8*)(Ab + arow1 + cs);
        bf16x8 b0 = *(const bf16x8*)(Bb + brow0 + cs);
        bf16x8 b1 = *(const bf16x8*)(Bb + brow1 + cs);
        bf16x8 b2 = *(const bf16x8*)(Bb + brow2 + cs);
        bf16x8 b3 = *(const bf16x8*)(Bb + brow3 + cs);
        acc[0][0] = __builtin_amdgcn_mfma_f32_16x16x32_bf16(a0, b0, acc[0][0], 0, 0, 0);
        acc[0][1] = __builtin_amdgcn_mfma_f32_16x16x32_bf16(a0, b1, acc[0][1], 0, 0, 0);
        acc[0][2] = __builtin_amdgcn_mfma_f32_16x16x32_bf16(a0, b2, acc[0][2], 0, 0, 0);
        acc[0][3] = __builtin_amdgcn_mfma_f32_16x16x32_bf16(a0, b3, acc[0][3], 0, 0, 0);
        acc[1][0] = __builtin_amdgcn_mfma_f32_16x16x32_bf16(a1, b0, acc[1][0], 0, 0, 0);
        acc[1][1] = __builtin_amdgcn_mfma_f32_16x16x32_bf16(a1, b1, acc[1][1], 0, 0, 0);
        acc[1][2] = __builtin_amdgcn_mfma_f32_16x16x32_bf16(a1, b2, acc[1][2], 0, 0, 0);
        acc[1][3] = __builtin_amdgcn_mfma_f32_16x16x32_bf16(a1, b3, acc[1][3], 0, 0, 0);
      }
    }

    // epilogue: d = c - 2s, pack (d | code), merge into per-cell top-2
#pragma unroll
    for (int fi = 0; fi < 2; ++fi) {
#pragma unroll
      for (int r = 0; r < 4; ++r) {
        float d0 = cf0 - 2.0f * acc[fi][0][r];
        float d1 = cf1 - 2.0f * acc[fi][1][r];
        float d2 = cf2 - 2.0f * acc[fi][2][r];
        float d3 = cf3 - 2.0f * acc[fi][3][r];
        float k0 = __uint_as_float((__float_as_uint(d0) & KMASK) | (unsigned)(codebase + 0));
        float k1 = __uint_as_float((__float_as_uint(d1) & KMASK) | (unsigned)(codebase + 16));
        float k2 = __uint_as_float((__float_as_uint(d2) & KMASK) | (unsigned)(codebase + 32));
        float k3 = __uint_as_float((__float_as_uint(d3) & KMASK) | (unsigned)(codebase + 48));
        float lo0 = fminf(k0, k2), hi0 = fmaxf(k0, k2);
        m2s[fi][r][0] = fminf(fminf(m2s[fi][r][0], fmaxf(m1s[fi][r][0], lo0)), hi0);
        m1s[fi][r][0] = fminf(m1s[fi][r][0], lo0);
        float lo1 = fminf(k1, k3), hi1 = fmaxf(k1, k3);
        m2s[fi][r][1] = fminf(fminf(m2s[fi][r][1], fmaxf(m1s[fi][r][1], lo1)), hi1);
        m1s[fi][r][1] = fminf(m1s[fi][r][1], lo1);
      }
    }
  }

  const int cid0 = split * 64 + wc * 32 + l15;
#pragma unroll
  for (int fi = 0; fi < 2; ++fi) {
#pragma unroll
    for (int r = 0; r < 4; ++r) {
      int token = tb * 64 + wr * 32 + fi * 16 + (lane >> 4) * 4 + r;
      float2* p = (float2*)(slotbuf + (size_t)token * 256);
      p[cid0]      = make_float2(m1s[fi][r][0], m2s[fi][r][0]);
      p[cid0 + 16] = make_float2(m1s[fi][r][1], m2s[fi][r][1]);
    }
  }
}

// one wave per token; exact f64 re-rank of margin candidates
__global__ void k_select(const float* __restrict__ slotbuf, const float* __restrict__ z,
                         const float* __restrict__ w, int* __restrict__ idxb,
                         unsigned int* __restrict__ counts) {
  const int lane = threadIdx.x & 63;
  const int t = blockIdx.x * 4 + (threadIdx.x >> 6);

  float4 e = *(const float4*)(slotbuf + (size_t)t * 256 + lane * 4);
  float p0 = e.x, p1 = e.y, p2 = e.z, p3 = e.w;  // cells 2*lane (p0,p1), 2*lane+1 (p2,p3)
  float pk = fminf(fminf(p0, p1), fminf(p2, p3));
#pragma unroll
  for (int m = 1; m < 64; m <<= 1) pk = fminf(pk, __shfl_xor(pk, m));
  const unsigned int mb = __float_as_uint(pk);
  int best = (int)(mb & 0x1FFFu);
  const float thr = __uint_as_float(mb & 0xFFFFE000u) + MARGIN;

  const unsigned int KM = 0xFFFFE000u;
  bool f0 = __uint_as_float(__float_as_uint(p0) & KM) < thr;
  bool f1 = __uint_as_float(__float_as_uint(p1) & KM) < thr;
  bool f2 = __uint_as_float(__float_as_uint(p2) & KM) < thr;
  bool f3 = __uint_as_float(__float_as_uint(p3) & KM) < thr;
  unsigned long long b0 = __ballot(f0), b1 = __ballot(f1);
  unsigned long long b2 = __ballot(f2), b3 = __ballot(f3);
  int nc = __popcll(b0) + __popcll(b1) + __popcll(b2) + __popcll(b3);

  if (nc > 1) {
    const float4* zp = (const float4*)(z + (size_t)t * DIM) + lane * 2;
    float4 za = zp[0], zc = zp[1];
    double bestd = 1e300;
    int besti = NE;

    auto eval = [&](int code) {
      const float4* wp = (const float4*)(w + (size_t)code * DIM) + lane * 2;
      float4 wa = wp[0], wv2 = wp[1];
      double d = (double)wa.x * ((double)wa.x - 2.0 * (double)za.x)
               + (double)wa.y * ((double)wa.y - 2.0 * (double)za.y)
               + (double)wa.z * ((double)wa.z - 2.0 * (double)za.z)
               + (double)wa.w * ((double)wa.w - 2.0 * (double)za.w)
               + (double)wv2.x * ((double)wv2.x - 2.0 * (double)zc.x)
               + (double)wv2.y * ((double)wv2.y - 2.0 * (double)zc.y)
               + (double)wv2.z * ((double)wv2.z - 2.0 * (double)zc.z)
               + (double)wv2.w * ((double)wv2.w - 2.0 * (double)zc.w);
#pragma unroll
      for (int m = 1; m < 64; m <<= 1) d += __shfl_xor(d, m);
      if (d < bestd || (d == bestd && code < besti)) { bestd = d; besti = code; }
    };
    auto scan_cell = [&](int cid) {
      int sp = cid >> 6, wcc = (cid >> 5) & 1, cls = cid & 31;
      for (int m2 = 0; m2 < 64; ++m2) {
        int code = sp * 4096 + (m2 >> 1) * 128 + wcc * 64 + (m2 & 1) * 32 + cls;
        eval(code);
      }
    };

    int i0 = (int)(__float_as_uint(p0) & 0x1FFFu);
    int i1 = (int)(__float_as_uint(p1) & 0x1FFFu);
    int i2 = (int)(__float_as_uint(p2) & 0x1FFFu);
    int i3 = (int)(__float_as_uint(p3) & 0x1FFFu);
    unsigned long long bm;
    bm = b0; while (bm) { int s = __ffsll(bm) - 1; bm &= bm - 1; eval(__shfl(i0, s)); }
    bm = b1; while (bm) { int s = __ffsll(bm) - 1; bm &= bm - 1; eval(__shfl(i1, s)); }
    bm = b2; while (bm) { int s = __ffsll(bm) - 1; bm &= bm - 1; eval(__shfl(i2, s)); }
    bm = b3; while (bm) { int s = __ffsll(bm) - 1; bm &= bm - 1; eval(__shfl(i3, s)); }
    unsigned long long h0 = __ballot(f0 && f1);
    unsigned long long h1 = __ballot(f2 && f3);
    bm = h0; while (bm) { int s = __ffsll(bm) - 1; bm &= bm - 1; scan_cell(2 * s); }
    bm = h1; while (bm) { int s = __ffsll(bm) - 1; bm &= bm - 1; scan_cell(2 * s + 1); }
    best = besti;
  }
  if (lane == 0) {
    idxb[t] = best;
    atomicAdd(&counts[best], 1u);
  }
}

__global__ void k_gather(const float* __restrict__ w, const int* __restrict__ idxb,
                         float* __restrict__ out) {
  int n = blockIdx.x * 2 + (threadIdx.x >> 7);
  int j = threadIdx.x & 127;
  int k = idxb[n];
  ((float4*)out)[(size_t)n * 128 + j] = ((const float4*)w)[(size_t)k * 128 + j];
}

__global__ void k_perp(const unsigned int* __restrict__ counts, float* __restrict__ out) {
  __shared__ float red[16];
  float s = 0.f;
  for (int k = threadIdx.x; k < NE; k += 1024) {
    float p = (float)counts[k] * (1.0f / (float)NTOK);
    s += p * logf(p + 1e-10f);
  }
#pragma unroll
  for (int m = 1; m < 64; m <<= 1) s += __shfl_xor(s, m);
  int lane = threadIdx.x & 63, wv = threadIdx.x >> 6;
  if (lane == 0) red[wv] = s;
  __syncthreads();
  if (threadIdx.x == 0) {
    float tot = 0.f;
    for (int i = 0; i < 16; ++i) tot += red[i];
    out[(size_t)NTOK * DIM] = expf(-tot);
  }
}

extern "C" void kernel_launch(void* const* d_in, const int* in_sizes, int n_in,
                              void* d_out, int out_size, void* d_ws, size_t ws_size,
                              hipStream_t stream) {
  const float* z = (const float*)d_in[0];
  const float* w = (const float*)d_in[1];
  float* out = (float*)d_out;
  char* ws = (char*)d_ws;

  unsigned int* zb      = (unsigned int*)(ws);
  unsigned int* wb      = (unsigned int*)(ws + 33554432);
  float*        cnorm   = (float*)(ws + 41943040);
  float*        slotbuf = (float*)(ws + 41975808);
  int*          idxb    = (int*)(ws + 75530240);
  unsigned int* counts  = (unsigned int*)(ws + 75661312);

  k_prep_z<<<8192, 256, 0, stream>>>(z, zb);
  k_prep_w<<<2048, 256, 0, stream>>>(w, wb, cnorm);
  k_phase1<<<1024, 256, 0, stream>>>((const unsigned short*)zb, (const unsigned short*)wb,
                                     cnorm, slotbuf);
  hipMemsetAsync(counts, 0, NE * sizeof(unsigned int), stream);
  k_select<<<8192, 256, 0, stream>>>(slotbuf, z, w, idxb, counts);
  k_gather<<<16384, 256, 0, stream>>>(w, idxb, out);
  k_perp<<<1, 1024, 0, stream>>>(counts, out);
}

// Round 2
// 448.533 us; speedup vs baseline: 1.1142x; 1.1142x over previous
//
#include <hip/hip_runtime.h>
#include <stdint.h>

// VectorQuantizer: z[32768,512] f32, weight[8192,512] f32 ->
//   out[0 .. 32768*512) = z_q = weight[argmin_k ||z-e_k||^2]  (exact fp32 rows)
//   out[32768*512]      = perplexity
//
// Pipeline:
//  1) k_prep_z / k_prep_w: fp32 -> bf16 copies (+ exact fp32 row norms c_k)
//  2) k_phase1: bf16-MFMA  d~ = c_k - 2 z.e_k ; 128x128 tile (m97 structure),
//     per token keep top-2 packed keys (quantized distance | 13-bit code idx)
//     per 128 code-cells -> slotbuf. Cell = (split, wc, col): 64 codes each.
//  3) k_select: global min; candidates within MARGIN re-ranked with exact f64
//     dots (hot cells fully rescanned); writes idx + histogram atomics
//  4) k_gather: z_q rows ; k_perp: perplexity
//
// ws layout (bytes):
//   zb    @ 0         : 32 MB  (bf16 z)
//   wb    @ 33554432  :  8 MB  (bf16 w)
//   cnorm @ 41943040  : 32 KB  (f32 ||e_k||^2)
//   slot  @ 41975808  : 32 MB  ([token][128 cells][2] f32 packed keys)
//   idx   @ 75530240  : 128 KB (i32)
//   counts@ 75661312  : 32 KB  (u32)

#define NTOK 32768
#define NE   8192
#define DIM  512
#define MARGIN 4.0f

typedef __attribute__((ext_vector_type(8))) short bf16x8;
typedef __attribute__((ext_vector_type(4))) float f32x4;

__device__ __forceinline__ unsigned int f2bf1(float x) {
  unsigned int u = __float_as_uint(x);
  return (u + 0x7FFFu + ((u >> 16) & 1u)) >> 16;
}
__device__ __forceinline__ unsigned int packbf2(float lo, float hi) {
  return f2bf1(lo) | (f2bf1(hi) << 16);
}

__device__ __forceinline__ void gl_lds16(const void* g, void* l) {
  __builtin_amdgcn_global_load_lds(
      (const __attribute__((address_space(1))) void*)g,
      (__attribute__((address_space(3))) void*)l, 16, 0, 0);
}

__global__ void k_prep_z(const float* __restrict__ z, unsigned int* __restrict__ zb) {
  int i = blockIdx.x * 256 + threadIdx.x;  // one thread per 8 floats; grid exact
  const float4* zp = (const float4*)z + (size_t)i * 2;
  float4 a = zp[0], b = zp[1];
  uint4 o;
  o.x = packbf2(a.x, a.y); o.y = packbf2(a.z, a.w);
  o.z = packbf2(b.x, b.y); o.w = packbf2(b.z, b.w);
  ((uint4*)zb)[i] = o;
}

__global__ void k_prep_w(const float* __restrict__ w, unsigned int* __restrict__ wb,
                         float* __restrict__ cnorm) {
  int row  = blockIdx.x * 4 + (threadIdx.x >> 6);  // one wave per code row
  int lane = threadIdx.x & 63;
  const float4* wp = (const float4*)(w + (size_t)row * DIM) + lane * 2;
  float4 a = wp[0], b = wp[1];
  uint4 o;
  o.x = packbf2(a.x, a.y); o.y = packbf2(a.z, a.w);
  o.z = packbf2(b.x, b.y); o.w = packbf2(b.z, b.w);
  ((uint4*)wb)[(size_t)row * 64 + lane] = o;
  float s = a.x * a.x + a.y * a.y + a.z * a.z + a.w * a.w
          + b.x * b.x + b.y * b.y + b.z * b.z + b.w * b.w;
#pragma unroll
  for (int m = 1; m < 64; m <<= 1) s += __shfl_xor(s, m);
  if (lane == 0) cnorm[row] = s;
}

// 256 thr = 4 waves (wr,wc in 2x2), tile 128 tokens x 128 codes, BK=64.
// Each wave owns a 64x64 sub-tile (4x4 frags of 16x16x32).
// grid: 1024 = 256 token-blocks x 4 code-splits (2048 codes = 16 ct tiles each).
// XCD-chunked swizzle: each XCD works one split -> its 2MB B-panel is L2-hot.
__global__ void __launch_bounds__(256) k_phase1(
    const unsigned short* __restrict__ zb, const unsigned short* __restrict__ wb,
    const float* __restrict__ cnorm, float* __restrict__ slotbuf) {
  __shared__ unsigned short Abuf[128 * 64];  // 16 KB [tok][k] bf16, xor-swizzled
  __shared__ unsigned short Bbuf[128 * 64];  // 16 KB [code][k]

  const int tid  = threadIdx.x;
  const int lane = tid & 63;
  const int wv   = tid >> 6;
  const int wr   = wv >> 1;
  const int wc   = wv & 1;
  // bijective XCD swizzle (nwg=1024, 8 XCDs, 128/chunk): same-XCD blocks get
  // one split (B L2-resident) and a contiguous tb range.
  const int swz   = (blockIdx.x & 7) * 128 + (blockIdx.x >> 3);
  const int split = swz >> 8;
  const int tb    = swz & 255;

  const int l8   = lane >> 3;
  const int l15  = lane & 15;
  // staging source col-byte, pre-swizzled so linear global_load_lds dest holds
  // element (row, col ^ ((row&7)<<4)); row&7 == lane>>3 for every issue.
  const int cbsw = ((lane & 7) ^ l8) << 4;

  const char* zsrc  = (const char*)zb + (size_t)(tb * 128 + wv * 32 + l8) * 1024 + cbsw;
  const char* wsrc0 = (const char*)wb + (size_t)(split * 2048 + wv * 32 + l8) * 1024 + cbsw;

  char* Ab = (char*)Abuf;
  char* Bb = (char*)Bbuf;
  char* dstA = Ab + wv * 4096;  // wave-uniform LDS bases (+lane*16 by HW)
  char* dstB = Bb + wv * 4096;

  // frag read col-bytes: (ks*64 + (lane>>4)*16) ^ ((lane&7)<<4)  (row&7==lane&7)
  const int csw0 = (((lane >> 4) << 4)) ^ ((lane & 7) << 4);
  const int csw1 = (64 + ((lane >> 4) << 4)) ^ ((lane & 7) << 4);
  int arow[4], brow[4];
#pragma unroll
  for (int i = 0; i < 4; ++i) {
    arow[i] = (wr * 64 + i * 16 + l15) << 7;
    brow[i] = (wc * 64 + i * 16 + l15) << 7;
  }

  const float BIG = 3.0e38f;
  float m1s[4][4], m2s[4][4];
#pragma unroll
  for (int mi = 0; mi < 4; ++mi)
#pragma unroll
    for (int r = 0; r < 4; ++r) { m1s[mi][r] = BIG; m2s[mi][r] = BIG; }

  const unsigned int KMASK = 0xFFFFE000u;

  for (int ct = 0; ct < 16; ++ct) {
    const int codebase = split * 2048 + ct * 128 + wc * 64 + l15;
    float cf0 = cnorm[codebase + 0];
    float cf1 = cnorm[codebase + 16];
    float cf2 = cnorm[codebase + 32];
    float cf3 = cnorm[codebase + 48];

    f32x4 acc[4][4];
    f32x4 zz = {0.f, 0.f, 0.f, 0.f};
#pragma unroll
    for (int fi = 0; fi < 4; ++fi)
#pragma unroll
      for (int fj = 0; fj < 4; ++fj) acc[fi][fj] = zz;

    const char* wct = wsrc0 + (size_t)ct * 128 * 1024;

    for (int kc = 0; kc < 8; ++kc) {
      __syncthreads();
      const char* ak = zsrc + kc * 128;
      gl_lds16(ak,         dstA);
      gl_lds16(ak + 8192,  dstA + 1024);
      gl_lds16(ak + 16384, dstA + 2048);
      gl_lds16(ak + 24576, dstA + 3072);
      const char* bk = wct + kc * 128;
      gl_lds16(bk,         dstB);
      gl_lds16(bk + 8192,  dstB + 1024);
      gl_lds16(bk + 16384, dstB + 2048);
      gl_lds16(bk + 24576, dstB + 3072);
      __syncthreads();
#pragma unroll
      for (int ks = 0; ks < 2; ++ks) {
        const int cs = ks ? csw1 : csw0;
        bf16x8 a[4], b[4];
#pragma unroll
        for (int i = 0; i < 4; ++i) {
          a[i] = *(const bf16x8*)(Ab + arow[i] + cs);
          b[i] = *(const bf16x8*)(Bb + brow[i] + cs);
        }
#pragma unroll
        for (int fi = 0; fi < 4; ++fi)
#pragma unroll
          for (int fj = 0; fj < 4; ++fj)
            acc[fi][fj] = __builtin_amdgcn_mfma_f32_16x16x32_bf16(a[fi], b[fj], acc[fi][fj], 0, 0, 0);
      }
    }

    // epilogue: d = c - 2s, pack (d | code), fold 4 n-frags into per-row top-2
#pragma unroll
    for (int mi = 0; mi < 4; ++mi) {
#pragma unroll
      for (int r = 0; r < 4; ++r) {
        float d0 = cf0 - 2.0f * acc[mi][0][r];
        float d1 = cf1 - 2.0f * acc[mi][1][r];
        float d2 = cf2 - 2.0f * acc[mi][2][r];
        float d3 = cf3 - 2.0f * acc[mi][3][r];
        float k0 = __uint_as_float((__float_as_uint(d0) & KMASK) | (unsigned)(codebase + 0));
        float k1 = __uint_as_float((__float_as_uint(d1) & KMASK) | (unsigned)(codebase + 16));
        float k2 = __uint_as_float((__float_as_uint(d2) & KMASK) | (unsigned)(codebase + 32));
        float k3 = __uint_as_float((__float_as_uint(d3) & KMASK) | (unsigned)(codebase + 48));
        float lo01 = fminf(k0, k1), hi01 = fmaxf(k0, k1);
        float lo23 = fminf(k2, k3), hi23 = fmaxf(k2, k3);
        float a1 = fminf(lo01, lo23);
        float a2 = fminf(fmaxf(lo01, lo23), fminf(hi01, hi23));
        float M1 = m1s[mi][r], M2 = m2s[mi][r];
        m2s[mi][r] = fminf(fminf(M2, a2), fmaxf(M1, a1));
        m1s[mi][r] = fminf(M1, a1);
      }
    }
  }

  // cell = split*32 + wc*16 + col  (64 codes: all ct, nf for this (split,wc,col))
  const int cell = split * 32 + wc * 16 + l15;
#pragma unroll
  for (int mi = 0; mi < 4; ++mi) {
#pragma unroll
    for (int r = 0; r < 4; ++r) {
      int token = tb * 128 + wr * 64 + mi * 16 + (lane >> 4) * 4 + r;
      float2* p = (float2*)(slotbuf + (size_t)token * 256);
      p[cell] = make_float2(m1s[mi][r], m2s[mi][r]);
    }
  }
}

// one wave per token; exact f64 re-rank of margin candidates
__global__ void k_select(const float* __restrict__ slotbuf, const float* __restrict__ z,
                         const float* __restrict__ w, int* __restrict__ idxb,
                         unsigned int* __restrict__ counts) {
  const int lane = threadIdx.x & 63;
  const int t = blockIdx.x * 4 + (threadIdx.x >> 6);

  float4 e = *(const float4*)(slotbuf + (size_t)t * 256 + lane * 4);
  float p0 = e.x, p1 = e.y, p2 = e.z, p3 = e.w;  // cells 2*lane (p0,p1), 2*lane+1 (p2,p3)
  float pk = fminf(fminf(p0, p1), fminf(p2, p3));
#pragma unroll
  for (int m = 1; m < 64; m <<= 1) pk = fminf(pk, __shfl_xor(pk, m));
  const unsigned int mb = __float_as_uint(pk);
  int best = (int)(mb & 0x1FFFu);
  const float thr = __uint_as_float(mb & 0xFFFFE000u) + MARGIN;

  const unsigned int KM = 0xFFFFE000u;
  bool f0 = __uint_as_float(__float_as_uint(p0) & KM) < thr;
  bool f1 = __uint_as_float(__float_as_uint(p1) & KM) < thr;
  bool f2 = __uint_as_float(__float_as_uint(p2) & KM) < thr;
  bool f3 = __uint_as_float(__float_as_uint(p3) & KM) < thr;
  unsigned long long b0 = __ballot(f0), b1 = __ballot(f1);
  unsigned long long b2 = __ballot(f2), b3 = __ballot(f3);
  int nc = __popcll(b0) + __popcll(b1) + __popcll(b2) + __popcll(b3);

  if (nc > 1) {
    const float4* zp = (const float4*)(z + (size_t)t * DIM) + lane * 2;
    float4 za = zp[0], zc = zp[1];
    double bestd = 1e300;
    int besti = NE;

    auto eval = [&](int code) {
      const float4* wp = (const float4*)(w + (size_t)code * DIM) + lane * 2;
      float4 wa = wp[0], wv2 = wp[1];
      double d = (double)wa.x * ((double)wa.x - 2.0 * (double)za.x)
               + (double)wa.y * ((double)wa.y - 2.0 * (double)za.y)
               + (double)wa.z * ((double)wa.z - 2.0 * (double)za.z)
               + (double)wa.w * ((double)wa.w - 2.0 * (double)za.w)
               + (double)wv2.x * ((double)wv2.x - 2.0 * (double)zc.x)
               + (double)wv2.y * ((double)wv2.y - 2.0 * (double)zc.y)
               + (double)wv2.z * ((double)wv2.z - 2.0 * (double)zc.z)
               + (double)wv2.w * ((double)wv2.w - 2.0 * (double)zc.w);
#pragma unroll
      for (int m = 1; m < 64; m <<= 1) d += __shfl_xor(d, m);
      if (d < bestd || (d == bestd && code < besti)) { bestd = d; besti = code; }
    };
    // cell = (split, wc, col): codes sp*2048 + ct*128 + wcc*64 + nf*16 + col
    auto scan_cell = [&](int cid) {
      int sp = cid >> 5, wcc = (cid >> 4) & 1, col = cid & 15;
      int base = sp * 2048 + wcc * 64 + col;
      for (int ct = 0; ct < 16; ++ct)
        for (int nf = 0; nf < 4; ++nf)
          eval(base + ct * 128 + nf * 16);
    };

    int i0 = (int)(__float_as_uint(p0) & 0x1FFFu);
    int i1 = (int)(__float_as_uint(p1) & 0x1FFFu);
    int i2 = (int)(__float_as_uint(p2) & 0x1FFFu);
    int i3 = (int)(__float_as_uint(p3) & 0x1FFFu);
    unsigned long long bm;
    bm = b0; while (bm) { int s = __ffsll(bm) - 1; bm &= bm - 1; eval(__shfl(i0, s)); }
    bm = b1; while (bm) { int s = __ffsll(bm) - 1; bm &= bm - 1; eval(__shfl(i1, s)); }
    bm = b2; while (bm) { int s = __ffsll(bm) - 1; bm &= bm - 1; eval(__shfl(i2, s)); }
    bm = b3; while (bm) { int s = __ffsll(bm) - 1; bm &= bm - 1; eval(__shfl(i3, s)); }
    unsigned long long h0 = __ballot(f0 && f1);
    unsigned long long h1 = __ballot(f2 && f3);
    bm = h0; while (bm) { int s = __ffsll(bm) - 1; bm &= bm - 1; scan_cell(2 * s); }
    bm = h1; while (bm) { int s = __ffsll(bm) - 1; bm &= bm - 1; scan_cell(2 * s + 1); }
    best = besti;
  }
  if (lane == 0) {
    idxb[t] = best;
    atomicAdd(&counts[best], 1u);
  }
}

__global__ void k_gather(const float* __restrict__ w, const int* __restrict__ idxb,
                         float* __restrict__ out) {
  int n = blockIdx.x * 2 + (threadIdx.x >> 7);
  int j = threadIdx.x & 127;
  int k = idxb[n];
  ((float4*)out)[(size_t)n * 128 + j] = ((const float4*)w)[(size_t)k * 128 + j];
}

__global__ void k_perp(const unsigned int* __restrict__ counts, float* __restrict__ out) {
  __shared__ float red[16];
  float s = 0.f;
  for (int k = threadIdx.x; k < NE; k += 1024) {
    float p = (float)counts[k] * (1.0f / (float)NTOK);
    s += p * logf(p + 1e-10f);
  }
#pragma unroll
  for (int m = 1; m < 64; m <<= 1) s += __shfl_xor(s, m);
  int lane = threadIdx.x & 63, wv = threadIdx.x >> 6;
  if (lane == 0) red[wv] = s;
  __syncthreads();
  if (threadIdx.x == 0) {
    float tot = 0.f;
    for (int i = 0; i < 16; ++i) tot += red[i];
    out[(size_t)NTOK * DIM] = expf(-tot);
  }
}

extern "C" void kernel_launch(void* const* d_in, const int* in_sizes, int n_in,
                              void* d_out, int out_size, void* d_ws, size_t ws_size,
                              hipStream_t stream) {
  const float* z = (const float*)d_in[0];
  const float* w = (const float*)d_in[1];
  float* out = (float*)d_out;
  char* ws = (char*)d_ws;

  unsigned int* zb      = (unsigned int*)(ws);
  unsigned int* wb      = (unsigned int*)(ws + 33554432);
  float*        cnorm   = (float*)(ws + 41943040);
  float*        slotbuf = (float*)(ws + 41975808);
  int*          idxb    = (int*)(ws + 75530240);
  unsigned int* counts  = (unsigned int*)(ws + 75661312);

  k_prep_z<<<8192, 256, 0, stream>>>(z, zb);
  k_prep_w<<<2048, 256, 0, stream>>>(w, wb, cnorm);
  k_phase1<<<1024, 256, 0, stream>>>((const unsigned short*)zb, (const unsigned short*)wb,
                                     cnorm, slotbuf);
  hipMemsetAsync(counts, 0, NE * sizeof(unsigned int), stream);
  k_select<<<8192, 256, 0, stream>>>(slotbuf, z, w, idxb, counts);
  k_gather<<<16384, 256, 0, stream>>>(w, idxb, out);
  k_perp<<<1, 1024, 0, stream>>>(counts, out);
}